// Round 10
// baseline (4250.389 us; speedup 1.0000x reference)
//
#include <hip/hip_runtime.h>
#include <hip/hip_bf16.h>
#include <cstdio>

#define B_ 32
#define T_ 512
#define E_ 256
#define H_ 512
#define L_ 48
#define G4 2048   // 4*H
#define NCOL 4096 // gates for both directions
#define BT (B_*T_)

typedef __attribute__((ext_vector_type(8))) short s8v;   // 8 bf16 (4 VGPRs)
typedef __attribute__((ext_vector_type(4))) float f4v;   // 4 f32 acc
typedef __hip_bfloat16 bf16;
typedef unsigned long long u64;
typedef unsigned int u32;

#define MFMA16(a,b,c) __builtin_amdgcn_mfma_f32_16x16x32_bf16((a),(b),(c),0,0,0)

// lgkm-only barrier: keeps vmem prefetch in flight across B1-B3
#define BAR_LGKM() asm volatile("s_waitcnt lgkmcnt(0)\n\ts_barrier" ::: "memory")
// full drain barrier: one per step, at B4 (publish visibility point)
#define BAR_VM()   asm volatile("s_waitcnt vmcnt(0) lgkmcnt(0)\n\ts_barrier" ::: "memory")

__device__ __forceinline__ float sigmf(float x){ return 1.0f/(1.0f+__expf(-x)); }
__device__ __forceinline__ float tanhfast(float x){ return 1.0f - 2.0f/(1.0f+__expf(2.0f*x)); }

// ---------------- K0: weight conversion + embedding gather ----------------
__global__ void k0_prep(const float* __restrict__ wih_f, const float* __restrict__ wih_b,
                        const float* __restrict__ whh_f, const float* __restrict__ whh_b,
                        const float* __restrict__ wemit, const float* __restrict__ emb,
                        const int* __restrict__ src,
                        bf16* __restrict__ wcat, bf16* __restrict__ whh,
                        bf16* __restrict__ wem, bf16* __restrict__ x)
{
    const int n1 = NCOL*E_;          // Wih_f ++ Wih_b -> [4096,256]
    const int n2 = 2*G4*H_;          // Whh_f, Whh_b   -> [2][2048,512]
    const int n3 = L_*1024;          // W_emit         -> [48,1024]
    const int n4 = BT*E_;            // x = emb[src]   -> [16384,256]
    const int total = n1+n2+n3+n4;
    for (int i = blockIdx.x*blockDim.x + threadIdx.x; i < total; i += gridDim.x*blockDim.x) {
        if (i < n1) {
            int r = i / E_, e = i - r*E_;
            float v = (r < G4) ? wih_f[r*E_ + e] : wih_b[(r-G4)*E_ + e];
            wcat[i] = __float2bfloat16(v);
        } else if (i < n1+n2) {
            int j = i - n1;
            int d = j / (G4*H_); int rem = j - d*(G4*H_);
            whh[j] = __float2bfloat16(d ? whh_b[rem] : whh_f[rem]);
        } else if (i < n1+n2+n3) {
            int j = i - n1 - n2;
            wem[j] = __float2bfloat16(wemit[j]);
        } else {
            int j = i - n1 - n2 - n3;
            int m = j >> 8, e = j & 255;
            int row = src[m];
            x[j] = __float2bfloat16(emb[(size_t)row*E_ + e]);
        }
    }
}

// ---------------- K1: xg = x @ Wcat^T + bias -> permuted bf16 layout ----------------
// layout: xg[dir][hblk=h/16][t][ (g*32+b)*16 + kk ]   (2048 bf16 contiguous per (dir,hblk,t))
__global__ __launch_bounds__(256) void k1_xg(const bf16* __restrict__ x, const bf16* __restrict__ wcat,
                                             const float* __restrict__ bf_, const float* __restrict__ bb_,
                                             bf16* __restrict__ xg)
{
    __shared__ bf16 a_lds[64*40];
    __shared__ bf16 b_lds[64*40];
    const int bx = blockIdx.x, by = blockIdx.y;
    const int tid = threadIdx.x;
    const int w = tid>>6, l = tid&63, lr = l&15, lk = (l>>4)*8;
    const int mh = (w>>1)*32, nh = (w&1)*32;
    f4v acc[2][2] = {};
    const int rS = tid>>2, cS = (tid&3)*8;
    for (int kc = 0; kc < E_; kc += 32) {
        *(s8v*)&a_lds[rS*40 + cS] = *(const s8v*)&x[(size_t)(bx*64 + rS)*E_ + kc + cS];
        *(s8v*)&b_lds[rS*40 + cS] = *(const s8v*)&wcat[(size_t)(by*64 + rS)*E_ + kc + cS];
        __syncthreads();
        s8v a0 = *(const s8v*)&a_lds[(mh+lr)*40 + lk];
        s8v a1 = *(const s8v*)&a_lds[(mh+16+lr)*40 + lk];
        s8v b0 = *(const s8v*)&b_lds[(nh+lr)*40 + lk];
        s8v b1 = *(const s8v*)&b_lds[(nh+16+lr)*40 + lk];
        acc[0][0] = MFMA16(a0,b0,acc[0][0]);
        acc[0][1] = MFMA16(a0,b1,acc[0][1]);
        acc[1][0] = MFMA16(a1,b0,acc[1][0]);
        acc[1][1] = MFMA16(a1,b1,acc[1][1]);
        __syncthreads();
    }
    #pragma unroll
    for (int nt=0; nt<2; nt++) {
        int col = by*64 + nh + nt*16 + lr;
        int dir = col >> 11, g = (col >> 9) & 3, hblk = (col & 511) >> 4, kk = col & 15;
        float bias = (col < G4) ? bf_[col] : bb_[col-G4];
        #pragma unroll
        for (int mt=0; mt<2; mt++) {
            int mrow = bx*64 + mh + mt*16 + (l>>4)*4;
            #pragma unroll
            for (int r=0;r<4;r++) {
                int row = mrow + r;
                int b = row >> 9, t = row & 511;
                size_t addr = ((((size_t)dir*32 + hblk)*512 + t)*2048) + (size_t)((g*32 + b)*16 + kk);
                xg[addr] = __float2bfloat16(acc[mt][nt][r] + bias);
            }
        }
    }
}

// ---------------- K2: bidirectional LSTM scan, XCD-local L2 exchange ----------------
// 1024 blocks; XCD0 first-32 tickets = forward chain, XCD1 first-32 = backward; rest exit.
// Exchange + flags via volatile ops on the shared per-XCD L2 (coherence point).
// Flags padded to 64B lines. 2-deep xg prefetch rotated at TOP; lgkm-only barriers
// at B1-B3 so the prefetch stays in flight; single vmcnt(0) drain at B4.
__global__ __launch_bounds__(256,1) void k2_scan(const bf16* __restrict__ whh,
        const bf16* __restrict__ xg, bf16* __restrict__ h_st,
        u32* __restrict__ hx, u32* __restrict__ flags, u32* __restrict__ tickets)
{
    __shared__ bf16 h_lds[32*520];          // h[t-1]: 32 b x 512 h (pad 8)
    __shared__ float g_lds[4][32][17];      // recurrent gate contributions
    __shared__ bf16 xg_lds[2048];           // this step's xg chunk
    __shared__ int sdead;
    __shared__ int s_slot;
    const int tid = threadIdx.x;

    u32 xcc;
    asm volatile("s_getreg_b32 %0, hwreg(HW_REG_XCC_ID)" : "=s"(xcc));
    if (tid == 0) {
        sdead = 0;
        s_slot = (xcc < 2u) ? (int)atomicAdd(&tickets[xcc], 1u) : 0x7fffffff;
    }
    __syncthreads();
    const int sblk = s_slot;
    if (xcc > 1u || sblk >= 32) return;      // block-uniform exit
    const int d = (int)xcc;
    const int k0g = sblk * 16;
    const int w = tid>>6, l = tid&63, lr = l&15, lk = (l>>4)*8;

    for (int i = tid; i < 4*32*17; i += 256) ((float*)g_lds)[i] = 0.f;

    // Whh slice in registers for the whole scan
    s8v breg[16];
    {
        const bf16* whh_d = whh + (size_t)d * G4 * H_;
        const int grow = w*512 + k0g + lr;
        #pragma unroll
        for (int ks=0; ks<16; ks++)
            breg[ks] = *(const s8v*)&whh_d[(size_t)grow*H_ + ks*32 + lk];
    }
    __syncthreads();

    bf16* h_d = h_st + (size_t)d * BT * H_;
    const bf16* xg_blk = xg + (((size_t)d*32 + sblk) * 512) * 2048;
    u32* hx_d32 = hx + (size_t)d * 16384;    // [slot][8192 u32], XCD-local
    u32* myflags = flags + d*512;            // flag p at myflags[p*16] (64B stride)

    // per-thread epilogue cells: batch cb, columns kg, kg+1 (c state in regs)
    const int cb = tid >> 3;                 // batch 0..31
    const int jj = tid & 7;                  // u32 word within 16-col slice
    const int kg = k0g + jj*2;
    float c0 = 0.f, c1 = 0.f;

    // 2-deep xg prefetch, rotated at TOP (slack ~1 full step before B4 drain)
    s8v xgA = *(const s8v*)&xg_blk[(size_t)(d ? T_-1 : 0)*2048 + tid*8];
    s8v xgB = *(const s8v*)&xg_blk[(size_t)(d ? T_-2 : 1)*2048 + tid*8];

    for (int s = 0; s < T_; s++) {
        const int t = d ? (T_-1-s) : s;
        // xg_lds overwrite safe: previous epilogue readers passed B4
        *(s8v*)&xg_lds[tid*8] = xgA;
        xgA = xgB;
        if (s + 2 < T_) {                     // issue s+2's chunk now
            const int tn = d ? (t-2) : (t+2);
            xgB = *(const s8v*)&xg_blk[(size_t)tn*2048 + tid*8];
        }
        if (s > 0 && w == 0) {
            // sleepless poll: 32 lanes, each its own 64B line, XCD-local L2
            const volatile u32* vf = (const volatile u32*)myflags;
            const u32 want = (u32)s;
            unsigned it = 0;
            for (;;) {
                u32 f = (l < 32) ? vf[l*16] : 0xFFFFFFFFu;
                if (__all((int)(f >= want))) break;
                if (++it > 3000000u) { sdead = 1; break; }
            }
        }
        BAR_LGKM();                           // B1: poll done (xg prefetch stays in flight)
        if (sdead) break;

        if (s > 0) {
            const u64* src64 = (const u64*)(hx_d32 + (size_t)((s-1)&1)*8192);
            u64 tmp[16];
            #pragma unroll
            for (int j = 0; j < 16; j++)
                tmp[j] = *(const volatile u64*)&src64[tid + j*256];   // L2-hit, linear 32KB
            #pragma unroll
            for (int j = 0; j < 16; j++) {
                int q = tid + j*256;             // 0..4095
                int p = q >> 7, rem = q & 127;   // producer, u64 within chunk
                int b = rem >> 2, g64 = rem & 3;
                *(u64*)&h_lds[b*520 + p*16 + g64*4] = tmp[j];
            }
        }
        BAR_LGKM();                           // B2: h_lds + xg_lds ready

        if (s > 0) {
            f4v acc0 = {}, acc1 = {};
            #pragma unroll
            for (int ks=0; ks<16; ks++) {
                s8v a0 = *(const s8v*)&h_lds[lr*520 + ks*32 + lk];
                s8v a1 = *(const s8v*)&h_lds[(16+lr)*520 + ks*32 + lk];
                acc0 = MFMA16(a0, breg[ks], acc0);
                acc1 = MFMA16(a1, breg[ks], acc1);
            }
            #pragma unroll
            for (int r=0;r<4;r++) {
                g_lds[w][(l>>4)*4 + r][lr]      = acc0[r];
                g_lds[w][16 + (l>>4)*4 + r][lr] = acc1[r];
            }
        }
        BAR_LGKM();                           // B3: g_lds ready

        // epilogue: 2 cells (cb, kg), (cb, kg+1)
        float hn0, hn1;
        #pragma unroll
        for (int cc = 0; cc < 2; cc++) {
            int kk = jj*2 + cc;
            float xi = __bfloat162float(xg_lds[(0*32+cb)*16 + kk]);
            float xf = __bfloat162float(xg_lds[(1*32+cb)*16 + kk]);
            float xgg= __bfloat162float(xg_lds[(2*32+cb)*16 + kk]);
            float xo = __bfloat162float(xg_lds[(3*32+cb)*16 + kk]);
            float gi = g_lds[0][cb][kk] + xi;
            float gf = g_lds[1][cb][kk] + xf;
            float gg = g_lds[2][cb][kk] + xgg;
            float go = g_lds[3][cb][kk] + xo;
            float ci = sigmf(gi), cf = sigmf(gf), cg = tanhfast(gg), co = sigmf(go);
            float cprev = cc ? c1 : c0;
            float cn = cf * cprev + ci * cg;
            if (cc) c1 = cn; else c0 = cn;
            float hn = co * tanhfast(cn);
            if (cc) hn1 = hn; else hn0 = hn;
        }
        bf16 h2[2] = { __float2bfloat16(hn0), __float2bfloat16(hn1) };
        u32 hp = *(u32*)h2;
        // publish to XCD-local exchange (volatile store -> shared L2)
        ((volatile u32*)hx_d32)[(size_t)(s&1)*8192 + sblk*256 + cb*8 + jj] = hp;
        BAR_VM();                             // B4: hx stores at L2 coherence point
        if (tid == 0)
            *(volatile u32*)&myflags[sblk*16] = (u32)(s+1);
        // off critical path: history for K3 (drains at NEXT step's B4)
        *(u32*)&h_d[((size_t)(cb*T_ + t))*H_ + kg] = hp;
    }
}

// ---------------- K3: emit = [h_f ++ h_b] @ W_emit^T + b_emit ----------------
__global__ __launch_bounds__(256) void k3_emit(const bf16* __restrict__ h_st, const bf16* __restrict__ wem,
                                               const float* __restrict__ bemit, float* __restrict__ emit)
{
    __shared__ bf16 a_lds[64*40];
    __shared__ bf16 b_lds[48*40];
    const int m0 = blockIdx.x * 64;
    const int tid = threadIdx.x;
    const int w = tid>>6, l = tid&63, lr = l&15, lk = (l>>4)*8;
    f4v acc[3] = {};
    const int rS = tid>>2, cS = (tid&3)*8;
    const int mS = m0 + rS, bS = mS >> 9, tS = mS & 511;
    for (int kc = 0; kc < 1024; kc += 32) {
        int k = kc + cS;
        int dir = k >> 9, kk = k & 511;
        *(s8v*)&a_lds[rS*40 + cS] = *(const s8v*)&h_st[(((size_t)dir*B_ + bS)*T_ + tS)*H_ + kk];
        if (tid < 192) {
            *(s8v*)&b_lds[rS*40 + cS] = *(const s8v*)&wem[(size_t)rS*1024 + kc + cS];
        }
        __syncthreads();
        s8v af = *(const s8v*)&a_lds[(w*16+lr)*40 + lk];
        #pragma unroll
        for (int nt=0; nt<3; nt++) {
            s8v bfr = *(const s8v*)&b_lds[(nt*16+lr)*40 + lk];
            acc[nt] = MFMA16(af, bfr, acc[nt]);
        }
        __syncthreads();
    }
    #pragma unroll
    for (int nt=0; nt<3; nt++) {
        int col = nt*16 + lr;
        float bias = bemit[col];
        int mrow = m0 + w*16 + (l>>4)*4;
        #pragma unroll
        for (int r=0;r<4;r++)
            emit[(size_t)(mrow+r)*L_ + col] = acc[nt][r] + bias;
    }
}

// ---------------- K4: golden score ----------------
__global__ void k4_golden(const float* __restrict__ emit, const int* __restrict__ targets,
                          const float* __restrict__ trans, float* __restrict__ gold)
{
    __shared__ float red[256];
    const int tid = threadIdx.x;
    float s = 0.f;
    for (int idx = blockIdx.x*256 + tid; idx < BT; idx += gridDim.x*256) {
        int t = idx & 511;
        int tgt = targets[idx];
        int prev = (t==0) ? 1 : targets[idx-1];   // BOS=1
        s += emit[(size_t)idx*L_ + tgt] + trans[prev*L_ + tgt];
    }
    red[tid] = s;
    __syncthreads();
    for (int o=128;o>0;o>>=1){ if (tid<o) red[tid]+=red[tid+o]; __syncthreads(); }
    if (tid==0) atomicAdd(gold, red[0]);
}

// ---------------- K5: CRF forward (one block per batch, trans in LDS) ----------------
__global__ void k5_crf(const float* __restrict__ emit, const float* __restrict__ trans,
                       float* __restrict__ apath)
{
    const int b = blockIdx.x, j = threadIdx.x;   // 64 threads
    __shared__ float trl[L_][L_+1];              // trl[i][j] = trans[i*48+j]
    __shared__ float albuf[2][64];
    for (int q = j; q < L_*L_; q += 64) trl[q/L_][q%L_] = trans[q];
    __syncthreads();
    float a = -3.0e38f;
    if (j < L_) a = emit[((size_t)b*T_)*L_ + j] + trl[1][j];   // alpha0, BOS row
    for (int t=1; t<T_; t++) {
        albuf[t&1][j] = a;
        __syncthreads();
        if (j < L_) {
            const float* buf = albuf[t&1];
            float m = -3.4e38f;
            #pragma unroll
            for (int i=0;i<L_;i++) m = fmaxf(m, buf[i] + trl[i][j]);
            float sum = 0.f;
            #pragma unroll
            for (int i=0;i<L_;i++) sum += __expf(buf[i] + trl[i][j] - m);
            a = m + __logf(sum) + emit[((size_t)b*T_ + t)*L_ + j];
        }
    }
    if (j == 2) apath[b] = a;    // EOS=2
}

// ---------------- K6: final scalar ----------------
__global__ void k6_final(const float* __restrict__ apath, const float* __restrict__ gold, float* out)
{
    if (threadIdx.x==0 && blockIdx.x==0) {
        float s=0.f;
        for (int b=0;b<B_;b++) s += apath[b];
        out[0] = (s - gold[0]) / (float)B_;
    }
}

extern "C" void kernel_launch(void* const* d_in, const int* in_sizes, int n_in,
                              void* d_out, int out_size, void* d_ws, size_t ws_size,
                              hipStream_t stream)
{
    const int*   src     = (const int*)d_in[0];
    const int*   targets = (const int*)d_in[2];
    const float* emb     = (const float*)d_in[3];
    const float* wih_f   = (const float*)d_in[4];
    const float* whh_f   = (const float*)d_in[5];
    const float* b_f     = (const float*)d_in[6];
    const float* wih_b   = (const float*)d_in[7];
    const float* whh_b   = (const float*)d_in[8];
    const float* b_b     = (const float*)d_in[9];
    const float* wemit   = (const float*)d_in[10];
    const float* bemit   = (const float*)d_in[11];
    const float* trans   = (const float*)d_in[12];

    char* ws = (char*)d_ws;
    size_t off = 0;
    auto alloc = [&](size_t bytes) -> void* {
        void* p = ws + off; off += (bytes + 255) & ~(size_t)255; return p;
    };
    bf16*  wcat  = (bf16*)alloc((size_t)NCOL*E_*2);      // 2 MB
    bf16*  whh   = (bf16*)alloc((size_t)2*G4*H_*2);      // 4 MB
    bf16*  wem   = (bf16*)alloc((size_t)L_*1024*2);      // 96 KB
    bf16*  x     = (bf16*)alloc((size_t)BT*E_*2);        // 8 MB
    bf16*  xg    = (bf16*)alloc((size_t)BT*NCOL*2);      // 128 MB (permuted layout)
    bf16*  h_st  = (bf16*)alloc((size_t)2*BT*H_*2);      // 32 MB
    float* emit  = (float*)alloc((size_t)BT*L_*4);       // 3 MB
    u32*   hx    = (u32*)alloc((size_t)2*2*8192*4);      // 128 KB XCD-local exchange
    u32*   flags = (u32*)alloc(4096);                    // 64 flags, 64B stride each
    u32*   tickets = (u32*)alloc(256);                   // per-XCD tickets
    float* gold  = (float*)alloc(256);
    float* apath = gold + 1;

    if (off > ws_size) {
        fprintf(stderr, "kernel_launch: workspace too small: need %zu, have %zu\n", off, ws_size);
        return;
    }

    // zero flags + tickets + gold/apath (contiguous region)
    hipMemsetAsync(flags, 0, 4096 + 512, stream);

    k0_prep<<<4096, 256, 0, stream>>>(wih_f, wih_b, whh_f, whh_b, wemit, emb, src,
                                      wcat, whh, wem, x);
    k1_xg<<<dim3(BT/64, NCOL/64), 256, 0, stream>>>(x, wcat, b_f, b_b, xg);
    k2_scan<<<1024, 256, 0, stream>>>(whh, xg, h_st, hx, flags, tickets);
    k3_emit<<<BT/64, 256, 0, stream>>>(h_st, wem, bemit, emit);
    k4_golden<<<64, 256, 0, stream>>>(emit, targets, trans, gold);
    k5_crf<<<B_, 64, 0, stream>>>(emit, trans, apath);
    k6_final<<<1, 64, 0, stream>>>(apath, gold, (float*)d_out);
}

// Round 11
// 3650.002 us; speedup vs baseline: 1.1645x; 1.1645x over previous
//
#include <hip/hip_runtime.h>
#include <hip/hip_bf16.h>
#include <cstdio>

#define B_ 32
#define T_ 512
#define E_ 256
#define H_ 512
#define L_ 48
#define G4 2048   // 4*H
#define NCOL 4096 // gates for both directions
#define BT (B_*T_)

typedef __attribute__((ext_vector_type(8))) short s8v;   // 8 bf16 (4 VGPRs)
typedef __attribute__((ext_vector_type(4))) float f4v;   // 4 f32 acc
typedef __hip_bfloat16 bf16;
typedef unsigned long long u64;
typedef unsigned int u32;

#define MFMA16(a,b,c) __builtin_amdgcn_mfma_f32_16x16x32_bf16((a),(b),(c),0,0,0)

// lgkm-only barrier: keeps vmem prefetch in flight across B1-B3
#define BAR_LGKM() asm volatile("s_waitcnt lgkmcnt(0)\n\ts_barrier" ::: "memory")

__device__ __forceinline__ float sigmf(float x){ return 1.0f/(1.0f+__expf(-x)); }
__device__ __forceinline__ float tanhfast(float x){ return 1.0f - 2.0f/(1.0f+__expf(2.0f*x)); }

// ---------------- K0: weight conversion + embedding gather ----------------
__global__ void k0_prep(const float* __restrict__ wih_f, const float* __restrict__ wih_b,
                        const float* __restrict__ whh_f, const float* __restrict__ whh_b,
                        const float* __restrict__ wemit, const float* __restrict__ emb,
                        const int* __restrict__ src,
                        bf16* __restrict__ wcat, bf16* __restrict__ whh,
                        bf16* __restrict__ wem, bf16* __restrict__ x)
{
    const int n1 = NCOL*E_;          // Wih_f ++ Wih_b -> [4096,256]
    const int n2 = 2*G4*H_;          // Whh_f, Whh_b   -> [2][2048,512]
    const int n3 = L_*1024;          // W_emit         -> [48,1024]
    const int n4 = BT*E_;            // x = emb[src]   -> [16384,256]
    const int total = n1+n2+n3+n4;
    for (int i = blockIdx.x*blockDim.x + threadIdx.x; i < total; i += gridDim.x*blockDim.x) {
        if (i < n1) {
            int r = i / E_, e = i - r*E_;
            float v = (r < G4) ? wih_f[r*E_ + e] : wih_b[(r-G4)*E_ + e];
            wcat[i] = __float2bfloat16(v);
        } else if (i < n1+n2) {
            int j = i - n1;
            int d = j / (G4*H_); int rem = j - d*(G4*H_);
            whh[j] = __float2bfloat16(d ? whh_b[rem] : whh_f[rem]);
        } else if (i < n1+n2+n3) {
            int j = i - n1 - n2;
            wem[j] = __float2bfloat16(wemit[j]);
        } else {
            int j = i - n1 - n2 - n3;
            int m = j >> 8, e = j & 255;
            int row = src[m];
            x[j] = __float2bfloat16(emb[(size_t)row*E_ + e]);
        }
    }
}

// ---------------- K1: xg = x @ Wcat^T + bias -> permuted bf16 layout ----------------
// layout: xg[dir][hblk=h/16][t][ (g*32+b)*16 + kk ]   (2048 bf16 contiguous per (dir,hblk,t))
__global__ __launch_bounds__(256) void k1_xg(const bf16* __restrict__ x, const bf16* __restrict__ wcat,
                                             const float* __restrict__ bf_, const float* __restrict__ bb_,
                                             bf16* __restrict__ xg)
{
    __shared__ bf16 a_lds[64*40];
    __shared__ bf16 b_lds[64*40];
    const int bx = blockIdx.x, by = blockIdx.y;
    const int tid = threadIdx.x;
    const int w = tid>>6, l = tid&63, lr = l&15, lk = (l>>4)*8;
    const int mh = (w>>1)*32, nh = (w&1)*32;
    f4v acc[2][2] = {};
    const int rS = tid>>2, cS = (tid&3)*8;
    for (int kc = 0; kc < E_; kc += 32) {
        *(s8v*)&a_lds[rS*40 + cS] = *(const s8v*)&x[(size_t)(bx*64 + rS)*E_ + kc + cS];
        *(s8v*)&b_lds[rS*40 + cS] = *(const s8v*)&wcat[(size_t)(by*64 + rS)*E_ + kc + cS];
        __syncthreads();
        s8v a0 = *(const s8v*)&a_lds[(mh+lr)*40 + lk];
        s8v a1 = *(const s8v*)&a_lds[(mh+16+lr)*40 + lk];
        s8v b0 = *(const s8v*)&b_lds[(nh+lr)*40 + lk];
        s8v b1 = *(const s8v*)&b_lds[(nh+16+lr)*40 + lk];
        acc[0][0] = MFMA16(a0,b0,acc[0][0]);
        acc[0][1] = MFMA16(a0,b1,acc[0][1]);
        acc[1][0] = MFMA16(a1,b0,acc[1][0]);
        acc[1][1] = MFMA16(a1,b1,acc[1][1]);
        __syncthreads();
    }
    #pragma unroll
    for (int nt=0; nt<2; nt++) {
        int col = by*64 + nh + nt*16 + lr;
        int dir = col >> 11, g = (col >> 9) & 3, hblk = (col & 511) >> 4, kk = col & 15;
        float bias = (col < G4) ? bf_[col] : bb_[col-G4];
        #pragma unroll
        for (int mt=0; mt<2; mt++) {
            int mrow = bx*64 + mh + mt*16 + (l>>4)*4;
            #pragma unroll
            for (int r=0;r<4;r++) {
                int row = mrow + r;
                int b = row >> 9, t = row & 511;
                size_t addr = ((((size_t)dir*32 + hblk)*512 + t)*2048) + (size_t)((g*32 + b)*16 + kk);
                xg[addr] = __float2bfloat16(acc[mt][nt][r] + bias);
            }
        }
    }
}

// ---------------- K2: bidirectional LSTM scan (R9 skeleton + lgkm barriers) ----------------
// 64 blocks: bid<32 forward, else backward. Each block owns 16 h-columns.
// hx (u32): [dir][slot][producer p][batch b][8 words]  (producer-major)
// flags: one per producer, padded to 64B lines: flags[d*512 + p*16]
__global__ __launch_bounds__(256,1) void k2_scan(const bf16* __restrict__ whh,
        const bf16* __restrict__ xg, bf16* __restrict__ h_st,
        u32* __restrict__ hx, u32* __restrict__ flags)
{
    __shared__ bf16 h_lds[32*520];          // h[t-1]: 32 b x 512 h (pad 8)
    __shared__ float g_lds[4][32][17];      // recurrent gate contributions
    __shared__ bf16 xg_lds[2048];           // this step's xg chunk
    __shared__ int sdead;
    const int tid = threadIdx.x;
    const int bid = blockIdx.x;
    const int d = bid >> 5, sblk = bid & 31;
    const int k0g = sblk * 16;
    const int w = tid>>6, l = tid&63, lr = l&15, lk = (l>>4)*8;

    if (tid == 0) sdead = 0;
    for (int i = tid; i < 4*32*17; i += 256) ((float*)g_lds)[i] = 0.f;

    // Whh slice in registers for the whole scan
    s8v breg[16];
    {
        const bf16* whh_d = whh + (size_t)d * G4 * H_;
        const int grow = w*512 + k0g + lr;
        #pragma unroll
        for (int ks=0; ks<16; ks++)
            breg[ks] = *(const s8v*)&whh_d[(size_t)grow*H_ + ks*32 + lk];
    }
    __syncthreads();

    bf16* h_d = h_st + (size_t)d * BT * H_;
    const bf16* xg_blk = xg + (((size_t)d*32 + sblk) * 512) * 2048;
    u32* hx_d32 = hx + (size_t)d * 16384;    // [slot][8192 u32]
    u32* myflags = flags + d*512;            // flag p at myflags[p*16] (64B stride)

    // per-thread epilogue cells: batch cb, columns kg, kg+1 (c state in regs)
    const int cb = tid >> 3;                 // batch 0..31
    const int jj = tid & 7;                  // u32 word within 16-col slice
    const int kg = k0g + jj*2;
    float c0 = 0.f, c1 = 0.f;

    // 2-deep xg prefetch, rotated at TOP; with lgkm-only B1-B3 the issued load
    // stays in flight until B4 (full step of slack)
    s8v xgA = *(const s8v*)&xg_blk[(size_t)(d ? T_-1 : 0)*2048 + tid*8];
    s8v xgB = *(const s8v*)&xg_blk[(size_t)(d ? T_-2 : 1)*2048 + tid*8];

    for (int s = 0; s < T_; s++) {
        const int t = d ? (T_-1-s) : s;
        // xg_lds overwrite safe: previous epilogue readers passed B4
        *(s8v*)&xg_lds[tid*8] = xgA;
        xgA = xgB;
        if (s + 2 < T_) {                     // issue s+2's chunk now
            const int tn = d ? (t-2) : (t+2);
            xgB = *(const s8v*)&xg_blk[(size_t)tn*2048 + tid*8];
        }
        if (s > 0 && w == 0) {
            // sleepless poll: 32 lanes, each its own 64B line
            const volatile u32* vf = (const volatile u32*)myflags;
            const u32 want = (u32)s;
            unsigned it = 0;
            for (;;) {
                u32 f = (l < 32) ? vf[l*16] : 0xFFFFFFFFu;
                if (__all((int)(f >= want))) break;
                if (++it > 3000000u) { sdead = 1; break; }
            }
        }
        BAR_LGKM();                           // B1: poll done (prefetch stays in flight)
        if (sdead) break;

        if (s > 0) {
            const u64* src64 = (const u64*)(hx_d32 + (size_t)((s-1)&1)*8192);
            u64 tmp[16];
            #pragma unroll
            for (int j = 0; j < 16; j++)
                tmp[j] = *(const volatile u64*)&src64[tid + j*256];   // linear 32KB
            #pragma unroll
            for (int j = 0; j < 16; j++) {
                int q = tid + j*256;             // 0..4095
                int p = q >> 7, rem = q & 127;   // producer, u64 within chunk
                int b = rem >> 2, g64 = rem & 3;
                *(u64*)&h_lds[b*520 + p*16 + g64*4] = tmp[j];
            }
        }
        BAR_LGKM();                           // B2: h_lds + xg_lds ready

        if (s > 0) {
            f4v acc0 = {}, acc1 = {};
            #pragma unroll
            for (int ks=0; ks<16; ks++) {
                s8v a0 = *(const s8v*)&h_lds[lr*520 + ks*32 + lk];
                s8v a1 = *(const s8v*)&h_lds[(16+lr)*520 + ks*32 + lk];
                acc0 = MFMA16(a0, breg[ks], acc0);
                acc1 = MFMA16(a1, breg[ks], acc1);
            }
            #pragma unroll
            for (int r=0;r<4;r++) {
                g_lds[w][(l>>4)*4 + r][lr]      = acc0[r];
                g_lds[w][16 + (l>>4)*4 + r][lr] = acc1[r];
            }
        }
        BAR_LGKM();                           // B3: g_lds ready

        // epilogue: 2 cells (cb, kg), (cb, kg+1)
        float hn0, hn1;
        #pragma unroll
        for (int cc = 0; cc < 2; cc++) {
            int kk = jj*2 + cc;
            float xi = __bfloat162float(xg_lds[(0*32+cb)*16 + kk]);
            float xf = __bfloat162float(xg_lds[(1*32+cb)*16 + kk]);
            float xgg= __bfloat162float(xg_lds[(2*32+cb)*16 + kk]);
            float xo = __bfloat162float(xg_lds[(3*32+cb)*16 + kk]);
            float gi = g_lds[0][cb][kk] + xi;
            float gf = g_lds[1][cb][kk] + xf;
            float gg = g_lds[2][cb][kk] + xgg;
            float go = g_lds[3][cb][kk] + xo;
            float ci = sigmf(gi), cf = sigmf(gf), cg = tanhfast(gg), co = sigmf(go);
            float cprev = cc ? c1 : c0;
            float cn = cf * cprev + ci * cg;
            if (cc) c1 = cn; else c0 = cn;
            float hn = co * tanhfast(cn);
            if (cc) hn1 = hn; else hn0 = hn;
        }
        bf16 h2[2] = { __float2bfloat16(hn0), __float2bfloat16(hn1) };
        u32 hp = *(u32*)h2;
        // producer-major exchange publish (agent scope, L3 coherence point)
        __hip_atomic_store(&hx_d32[(size_t)(s&1)*8192 + sblk*256 + cb*8 + jj], hp,
                           __ATOMIC_RELAXED, __HIP_MEMORY_SCOPE_AGENT);
        __syncthreads();                      // B4: vmcnt(0) — hx publish retired
        if (tid == 0)
            __hip_atomic_store(&myflags[sblk*16], (u32)(s+1),
                               __ATOMIC_RELAXED, __HIP_MEMORY_SCOPE_AGENT);
        // off critical path: history for K3 (drains at NEXT step's B4)
        *(u32*)&h_d[((size_t)(cb*T_ + t))*H_ + kg] = hp;
    }
}

// ---------------- K3: emit = [h_f ++ h_b] @ W_emit^T + b_emit ----------------
__global__ __launch_bounds__(256) void k3_emit(const bf16* __restrict__ h_st, const bf16* __restrict__ wem,
                                               const float* __restrict__ bemit, float* __restrict__ emit)
{
    __shared__ bf16 a_lds[64*40];
    __shared__ bf16 b_lds[48*40];
    const int m0 = blockIdx.x * 64;
    const int tid = threadIdx.x;
    const int w = tid>>6, l = tid&63, lr = l&15, lk = (l>>4)*8;
    f4v acc[3] = {};
    const int rS = tid>>2, cS = (tid&3)*8;
    const int mS = m0 + rS, bS = mS >> 9, tS = mS & 511;
    for (int kc = 0; kc < 1024; kc += 32) {
        int k = kc + cS;
        int dir = k >> 9, kk = k & 511;
        *(s8v*)&a_lds[rS*40 + cS] = *(const s8v*)&h_st[(((size_t)dir*B_ + bS)*T_ + tS)*H_ + kk];
        if (tid < 192) {
            *(s8v*)&b_lds[rS*40 + cS] = *(const s8v*)&wem[(size_t)rS*1024 + kc + cS];
        }
        __syncthreads();
        s8v af = *(const s8v*)&a_lds[(w*16+lr)*40 + lk];
        #pragma unroll
        for (int nt=0; nt<3; nt++) {
            s8v bfr = *(const s8v*)&b_lds[(nt*16+lr)*40 + lk];
            acc[nt] = MFMA16(af, bfr, acc[nt]);
        }
        __syncthreads();
    }
    #pragma unroll
    for (int nt=0; nt<3; nt++) {
        int col = nt*16 + lr;
        float bias = bemit[col];
        int mrow = m0 + w*16 + (l>>4)*4;
        #pragma unroll
        for (int r=0;r<4;r++)
            emit[(size_t)(mrow+r)*L_ + col] = acc[nt][r] + bias;
    }
}

// ---------------- K4: golden score ----------------
__global__ void k4_golden(const float* __restrict__ emit, const int* __restrict__ targets,
                          const float* __restrict__ trans, float* __restrict__ gold)
{
    __shared__ float red[256];
    const int tid = threadIdx.x;
    float s = 0.f;
    for (int idx = blockIdx.x*256 + tid; idx < BT; idx += gridDim.x*256) {
        int t = idx & 511;
        int tgt = targets[idx];
        int prev = (t==0) ? 1 : targets[idx-1];   // BOS=1
        s += emit[(size_t)idx*L_ + tgt] + trans[prev*L_ + tgt];
    }
    red[tid] = s;
    __syncthreads();
    for (int o=128;o>0;o>>=1){ if (tid<o) red[tid]+=red[tid+o]; __syncthreads(); }
    if (tid==0) atomicAdd(gold, red[0]);
}

// ---------------- K5: CRF forward (one block per batch, trans in LDS) ----------------
__global__ void k5_crf(const float* __restrict__ emit, const float* __restrict__ trans,
                       float* __restrict__ apath)
{
    const int b = blockIdx.x, j = threadIdx.x;   // 64 threads
    __shared__ float trl[L_][L_+1];              // trl[i][j] = trans[i*48+j]
    __shared__ float albuf[2][64];
    for (int q = j; q < L_*L_; q += 64) trl[q/L_][q%L_] = trans[q];
    __syncthreads();
    float a = -3.0e38f;
    if (j < L_) a = emit[((size_t)b*T_)*L_ + j] + trl[1][j];   // alpha0, BOS row
    for (int t=1; t<T_; t++) {
        albuf[t&1][j] = a;
        __syncthreads();
        if (j < L_) {
            const float* buf = albuf[t&1];
            float m = -3.4e38f;
            #pragma unroll
            for (int i=0;i<L_;i++) m = fmaxf(m, buf[i] + trl[i][j]);
            float sum = 0.f;
            #pragma unroll
            for (int i=0;i<L_;i++) sum += __expf(buf[i] + trl[i][j] - m);
            a = m + __logf(sum) + emit[((size_t)b*T_ + t)*L_ + j];
        }
    }
    if (j == 2) apath[b] = a;    // EOS=2
}

// ---------------- K6: final scalar ----------------
__global__ void k6_final(const float* __restrict__ apath, const float* __restrict__ gold, float* out)
{
    if (threadIdx.x==0 && blockIdx.x==0) {
        float s=0.f;
        for (int b=0;b<B_;b++) s += apath[b];
        out[0] = (s - gold[0]) / (float)B_;
    }
}

extern "C" void kernel_launch(void* const* d_in, const int* in_sizes, int n_in,
                              void* d_out, int out_size, void* d_ws, size_t ws_size,
                              hipStream_t stream)
{
    const int*   src     = (const int*)d_in[0];
    const int*   targets = (const int*)d_in[2];
    const float* emb     = (const float*)d_in[3];
    const float* wih_f   = (const float*)d_in[4];
    const float* whh_f   = (const float*)d_in[5];
    const float* b_f     = (const float*)d_in[6];
    const float* wih_b   = (const float*)d_in[7];
    const float* whh_b   = (const float*)d_in[8];
    const float* b_b     = (const float*)d_in[9];
    const float* wemit   = (const float*)d_in[10];
    const float* bemit   = (const float*)d_in[11];
    const float* trans   = (const float*)d_in[12];

    char* ws = (char*)d_ws;
    size_t off = 0;
    auto alloc = [&](size_t bytes) -> void* {
        void* p = ws + off; off += (bytes + 255) & ~(size_t)255; return p;
    };
    bf16*  wcat  = (bf16*)alloc((size_t)NCOL*E_*2);      // 2 MB
    bf16*  whh   = (bf16*)alloc((size_t)2*G4*H_*2);      // 4 MB
    bf16*  wem   = (bf16*)alloc((size_t)L_*1024*2);      // 96 KB
    bf16*  x     = (bf16*)alloc((size_t)BT*E_*2);        // 8 MB
    bf16*  xg    = (bf16*)alloc((size_t)BT*NCOL*2);      // 128 MB (permuted layout)
    bf16*  h_st  = (bf16*)alloc((size_t)2*BT*H_*2);      // 32 MB
    float* emit  = (float*)alloc((size_t)BT*L_*4);       // 3 MB
    u32*   hx    = (u32*)alloc((size_t)2*2*8192*4);      // 128 KB exchange
    u32*   flags = (u32*)alloc(4096);                    // 64 flags, 64B stride each
    float* gold  = (float*)alloc(256);
    float* apath = gold + 1;

    if (off > ws_size) {
        fprintf(stderr, "kernel_launch: workspace too small: need %zu, have %zu\n", off, ws_size);
        return;
    }

    // zero flags + gold/apath (contiguous region)
    hipMemsetAsync(flags, 0, 4096 + 256, stream);

    k0_prep<<<4096, 256, 0, stream>>>(wih_f, wih_b, whh_f, whh_b, wemit, emb, src,
                                      wcat, whh, wem, x);
    k1_xg<<<dim3(BT/64, NCOL/64), 256, 0, stream>>>(x, wcat, b_f, b_b, xg);
    k2_scan<<<64, 256, 0, stream>>>(whh, xg, h_st, hx, flags);
    k3_emit<<<BT/64, 256, 0, stream>>>(h_st, wem, bemit, emit);
    k4_golden<<<64, 256, 0, stream>>>(emit, targets, trans, gold);
    k5_crf<<<B_, 64, 0, stream>>>(emit, trans, apath);
    k6_final<<<1, 64, 0, stream>>>(apath, gold, (float*)d_out);
}

// Round 12
// 2991.545 us; speedup vs baseline: 1.4208x; 1.2201x over previous
//
#include <hip/hip_runtime.h>
#include <hip/hip_bf16.h>
#include <cstdio>

#define B_ 32
#define T_ 512
#define E_ 256
#define H_ 512
#define L_ 48
#define G4 2048   // 4*H
#define NCOL 4096 // gates for both directions
#define BT (B_*T_)

typedef __attribute__((ext_vector_type(8))) short s8v;   // 8 bf16 (4 VGPRs)
typedef __attribute__((ext_vector_type(4))) float f4v;   // 4 f32 acc
typedef __hip_bfloat16 bf16;
typedef unsigned long long u64;
typedef unsigned int u32;

#define MFMA16(a,b,c) __builtin_amdgcn_mfma_f32_16x16x32_bf16((a),(b),(c),0,0,0)

// lgkm-only barrier: never drains vmem (prefetch + publish stay in flight)
#define BAR_LGKM() asm volatile("s_waitcnt lgkmcnt(0)\n\ts_barrier" ::: "memory")

__device__ __forceinline__ float sigmf(float x){ return 1.0f/(1.0f+__expf(-x)); }
__device__ __forceinline__ float tanhfast(float x){ return 1.0f - 2.0f/(1.0f+__expf(2.0f*x)); }

// ---------------- K0: weight conversion + embedding gather ----------------
__global__ void k0_prep(const float* __restrict__ wih_f, const float* __restrict__ wih_b,
                        const float* __restrict__ whh_f, const float* __restrict__ whh_b,
                        const float* __restrict__ wemit, const float* __restrict__ emb,
                        const int* __restrict__ src,
                        bf16* __restrict__ wcat, bf16* __restrict__ whh,
                        bf16* __restrict__ wem, bf16* __restrict__ x)
{
    const int n1 = NCOL*E_;          // Wih_f ++ Wih_b -> [4096,256]
    const int n2 = 2*G4*H_;          // Whh_f, Whh_b   -> [2][2048,512]
    const int n3 = L_*1024;          // W_emit         -> [48,1024]
    const int n4 = BT*E_;            // x = emb[src]   -> [16384,256]
    const int total = n1+n2+n3+n4;
    for (int i = blockIdx.x*blockDim.x + threadIdx.x; i < total; i += gridDim.x*blockDim.x) {
        if (i < n1) {
            int r = i / E_, e = i - r*E_;
            float v = (r < G4) ? wih_f[r*E_ + e] : wih_b[(r-G4)*E_ + e];
            wcat[i] = __float2bfloat16(v);
        } else if (i < n1+n2) {
            int j = i - n1;
            int d = j / (G4*H_); int rem = j - d*(G4*H_);
            whh[j] = __float2bfloat16(d ? whh_b[rem] : whh_f[rem]);
        } else if (i < n1+n2+n3) {
            int j = i - n1 - n2;
            wem[j] = __float2bfloat16(wemit[j]);
        } else {
            int j = i - n1 - n2 - n3;
            int m = j >> 8, e = j & 255;
            int row = src[m];
            x[j] = __float2bfloat16(emb[(size_t)row*E_ + e]);
        }
    }
}

// ---------------- K1: xg = x @ Wcat^T + bias -> permuted bf16 layout ----------------
// layout: xg[dir][hblk=h/16][t][ (g*32+b)*16 + kk ]   (2048 bf16 contiguous per (dir,hblk,t))
__global__ __launch_bounds__(256) void k1_xg(const bf16* __restrict__ x, const bf16* __restrict__ wcat,
                                             const float* __restrict__ bf_, const float* __restrict__ bb_,
                                             bf16* __restrict__ xg)
{
    __shared__ bf16 a_lds[64*40];
    __shared__ bf16 b_lds[64*40];
    const int bx = blockIdx.x, by = blockIdx.y;
    const int tid = threadIdx.x;
    const int w = tid>>6, l = tid&63, lr = l&15, lk = (l>>4)*8;
    const int mh = (w>>1)*32, nh = (w&1)*32;
    f4v acc[2][2] = {};
    const int rS = tid>>2, cS = (tid&3)*8;
    for (int kc = 0; kc < E_; kc += 32) {
        *(s8v*)&a_lds[rS*40 + cS] = *(const s8v*)&x[(size_t)(bx*64 + rS)*E_ + kc + cS];
        *(s8v*)&b_lds[rS*40 + cS] = *(const s8v*)&wcat[(size_t)(by*64 + rS)*E_ + kc + cS];
        __syncthreads();
        s8v a0 = *(const s8v*)&a_lds[(mh+lr)*40 + lk];
        s8v a1 = *(const s8v*)&a_lds[(mh+16+lr)*40 + lk];
        s8v b0 = *(const s8v*)&b_lds[(nh+lr)*40 + lk];
        s8v b1 = *(const s8v*)&b_lds[(nh+16+lr)*40 + lk];
        acc[0][0] = MFMA16(a0,b0,acc[0][0]);
        acc[0][1] = MFMA16(a0,b1,acc[0][1]);
        acc[1][0] = MFMA16(a1,b0,acc[1][0]);
        acc[1][1] = MFMA16(a1,b1,acc[1][1]);
        __syncthreads();
    }
    #pragma unroll
    for (int nt=0; nt<2; nt++) {
        int col = by*64 + nh + nt*16 + lr;
        int dir = col >> 11, g = (col >> 9) & 3, hblk = (col & 511) >> 4, kk = col & 15;
        float bias = (col < G4) ? bf_[col] : bb_[col-G4];
        #pragma unroll
        for (int mt=0; mt<2; mt++) {
            int mrow = bx*64 + mh + mt*16 + (l>>4)*4;
            #pragma unroll
            for (int r=0;r<4;r++) {
                int row = mrow + r;
                int b = row >> 9, t = row & 511;
                size_t addr = ((((size_t)dir*32 + hblk)*512 + t)*2048) + (size_t)((g*32 + b)*16 + kk);
                xg[addr] = __float2bfloat16(acc[mt][nt][r] + bias);
            }
        }
    }
}

// ---------------- K2: bidirectional LSTM scan, fused tagged-data exchange ----------------
// 64 blocks: bid<32 forward, else backward. Each block owns 16 h-columns.
// hx (u64): [dir][slot][producer p][b*8+jj]; word = (tag<<32)|(2 bf16 payload).
// Consumer thread tid polls its 32 coalesced words slot[j*256+tid] (j=producer):
// detect-on-data fuses publish-visibility, flag, and bulk-load into ONE hop.
// No vmem drains anywhere in the loop.
__global__ __launch_bounds__(256,1) void k2_scan(const bf16* __restrict__ whh,
        const bf16* __restrict__ xg, bf16* __restrict__ h_st,
        u64* __restrict__ hx)
{
    __shared__ bf16 h_lds[32*520];          // h[t-1]: 32 b x 512 h (pad 8)
    __shared__ float g_lds[4][32][17];      // recurrent gate contributions
    __shared__ bf16 xg_lds[2048];           // this step's xg chunk
    __shared__ int sdead;
    const int tid = threadIdx.x;
    const int bid = blockIdx.x;
    const int d = bid >> 5, sblk = bid & 31;
    const int k0g = sblk * 16;
    const int w = tid>>6, l = tid&63, lr = l&15, lk = (l>>4)*8;

    if (tid == 0) sdead = 0;
    for (int i = tid; i < 4*32*17; i += 256) ((float*)g_lds)[i] = 0.f;

    // Whh slice in registers for the whole scan
    s8v breg[16];
    {
        const bf16* whh_d = whh + (size_t)d * G4 * H_;
        const int grow = w*512 + k0g + lr;
        #pragma unroll
        for (int ks=0; ks<16; ks++)
            breg[ks] = *(const s8v*)&whh_d[(size_t)grow*H_ + ks*32 + lk];
    }
    __syncthreads();

    // history layout: h_st[d][t][hblk=32][b=32][16 cols] (coalesced 1KB/block/step)
    bf16* h_d = h_st + (size_t)d * T_ * 32 * 32 * 16;
    const bf16* xg_blk = xg + (((size_t)d*32 + sblk) * 512) * 2048;
    u64* hx_d = hx + (size_t)d * 16384;      // [slot][8192 u64]

    // per-thread epilogue cells: batch cb, columns kg, kg+1 (c state in regs)
    const int cb = tid >> 3;                 // batch 0..31
    const int jj = tid & 7;                  // word within 16-col slice
    float c0 = 0.f, c1 = 0.f;
    u32* hl32 = (u32*)h_lds;                 // u32 idx: b*260 + p*8 + jj
    const int lbase = (tid>>3)*260 + (tid&7);

    // 2-deep xg prefetch, rotated at TOP (stays in flight across lgkm barriers)
    s8v xgA = *(const s8v*)&xg_blk[(size_t)(d ? T_-1 : 0)*2048 + tid*8];
    s8v xgB = *(const s8v*)&xg_blk[(size_t)(d ? T_-2 : 1)*2048 + tid*8];

    for (int s = 0; s < T_; s++) {
        const int t = d ? (T_-1-s) : s;
        // xg_lds overwrite safe: previous epilogue readers passed B4'
        *(s8v*)&xg_lds[tid*8] = xgA;
        xgA = xgB;
        if (s + 2 < T_) {
            const int tn = d ? (t-2) : (t+2);
            xgB = *(const s8v*)&xg_blk[(size_t)tn*2048 + tid*8];
        }

        if (s > 0) {
            // fused poll+load: thread tid owns word tid of each producer j
            const u64* slot = hx_d + (size_t)((s-1)&1)*8192;
            const u32 want = (u32)s;
            u32 pend = 0xFFFFFFFFu;
            int guard = 0;
            while (pend) {
                u64 v[32];
                #pragma unroll
                for (int j = 0; j < 32; j++)
                    if (pend & (1u<<j))
                        v[j] = __hip_atomic_load(&slot[j*256 + tid],
                                                 __ATOMIC_RELAXED, __HIP_MEMORY_SCOPE_AGENT);
                #pragma unroll
                for (int j = 0; j < 32; j++)
                    if ((pend & (1u<<j)) && (u32)(v[j] >> 32) == want) {
                        hl32[lbase + j*8] = (u32)v[j];
                        pend &= ~(1u<<j);
                    }
                if (++guard > 100000) { sdead = 1; break; }
            }
        }
        BAR_LGKM();                           // B2: h_lds + xg_lds ready
        if (sdead) break;

        if (s > 0) {
            f4v acc0 = {}, acc1 = {};
            #pragma unroll
            for (int ks=0; ks<16; ks++) {
                s8v a0 = *(const s8v*)&h_lds[lr*520 + ks*32 + lk];
                s8v a1 = *(const s8v*)&h_lds[(16+lr)*520 + ks*32 + lk];
                acc0 = MFMA16(a0, breg[ks], acc0);
                acc1 = MFMA16(a1, breg[ks], acc1);
            }
            #pragma unroll
            for (int r=0;r<4;r++) {
                g_lds[w][(l>>4)*4 + r][lr]      = acc0[r];
                g_lds[w][16 + (l>>4)*4 + r][lr] = acc1[r];
            }
        }
        BAR_LGKM();                           // B3: g_lds ready

        // epilogue: 2 cells (cb, kg), (cb, kg+1)
        float hn0, hn1;
        #pragma unroll
        for (int cc = 0; cc < 2; cc++) {
            int kk = jj*2 + cc;
            float xi = __bfloat162float(xg_lds[(0*32+cb)*16 + kk]);
            float xf = __bfloat162float(xg_lds[(1*32+cb)*16 + kk]);
            float xgg= __bfloat162float(xg_lds[(2*32+cb)*16 + kk]);
            float xo = __bfloat162float(xg_lds[(3*32+cb)*16 + kk]);
            float gi = g_lds[0][cb][kk] + xi;
            float gf = g_lds[1][cb][kk] + xf;
            float gg = g_lds[2][cb][kk] + xgg;
            float go = g_lds[3][cb][kk] + xo;
            float ci = sigmf(gi), cf = sigmf(gf), cg = tanhfast(gg), co = sigmf(go);
            float cprev = cc ? c1 : c0;
            float cn = cf * cprev + ci * cg;
            if (cc) c1 = cn; else c0 = cn;
            float hn = co * tanhfast(cn);
            if (cc) hn1 = hn; else hn0 = hn;
        }
        bf16 h2[2] = { __float2bfloat16(hn0), __float2bfloat16(hn1) };
        u32 hp = *(u32*)h2;
        // tagged fire-and-forget publication: validity travels with the data
        u64 pk = ((u64)(u32)(s+1) << 32) | (u64)hp;
        __hip_atomic_store(&hx_d[(size_t)(s&1)*8192 + sblk*256 + cb*8 + jj], pk,
                           __ATOMIC_RELAXED, __HIP_MEMORY_SCOPE_AGENT);
        // coalesced history store (1KB contiguous per block per step)
        *(u32*)&h_d[(((size_t)t*32 + sblk)*32 + cb)*16 + jj*2] = hp;
        BAR_LGKM();                           // B4': LDS reuse protection only
    }
}

// ---------------- K3: emit = [h_f ++ h_b] @ W_emit^T + b_emit ----------------
// h_st layout: [dir][t][hblk][b][16]
__global__ __launch_bounds__(256) void k3_emit(const bf16* __restrict__ h_st, const bf16* __restrict__ wem,
                                               const float* __restrict__ bemit, float* __restrict__ emit)
{
    __shared__ bf16 a_lds[64*40];
    __shared__ bf16 b_lds[48*40];
    const int m0 = blockIdx.x * 64;
    const int tid = threadIdx.x;
    const int w = tid>>6, l = tid&63, lr = l&15, lk = (l>>4)*8;
    f4v acc[3] = {};
    const int rS = tid>>2, cS = (tid&3)*8;
    const int mS = m0 + rS, bS = mS >> 9, tS = mS & 511;
    for (int kc = 0; kc < 1024; kc += 32) {
        int k = kc + cS;
        int dir = k >> 9, kk = k & 511;
        int hblk = kk >> 4, k16 = kk & 15;
        *(s8v*)&a_lds[rS*40 + cS] =
            *(const s8v*)&h_st[((((size_t)dir*T_ + tS)*32 + hblk)*32 + bS)*16 + k16];
        if (tid < 192) {
            *(s8v*)&b_lds[rS*40 + cS] = *(const s8v*)&wem[(size_t)rS*1024 + kc + cS];
        }
        __syncthreads();
        s8v af = *(const s8v*)&a_lds[(w*16+lr)*40 + lk];
        #pragma unroll
        for (int nt=0; nt<3; nt++) {
            s8v bfr = *(const s8v*)&b_lds[(nt*16+lr)*40 + lk];
            acc[nt] = MFMA16(af, bfr, acc[nt]);
        }
        __syncthreads();
    }
    #pragma unroll
    for (int nt=0; nt<3; nt++) {
        int col = nt*16 + lr;
        float bias = bemit[col];
        int mrow = m0 + w*16 + (l>>4)*4;
        #pragma unroll
        for (int r=0;r<4;r++)
            emit[(size_t)(mrow+r)*L_ + col] = acc[nt][r] + bias;
    }
}

// ---------------- K4: golden score ----------------
__global__ void k4_golden(const float* __restrict__ emit, const int* __restrict__ targets,
                          const float* __restrict__ trans, float* __restrict__ gold)
{
    __shared__ float red[256];
    const int tid = threadIdx.x;
    float s = 0.f;
    for (int idx = blockIdx.x*256 + tid; idx < BT; idx += gridDim.x*256) {
        int t = idx & 511;
        int tgt = targets[idx];
        int prev = (t==0) ? 1 : targets[idx-1];   // BOS=1
        s += emit[(size_t)idx*L_ + tgt] + trans[prev*L_ + tgt];
    }
    red[tid] = s;
    __syncthreads();
    for (int o=128;o>0;o>>=1){ if (tid<o) red[tid]+=red[tid+o]; __syncthreads(); }
    if (tid==0) atomicAdd(gold, red[0]);
}

// ---------------- K5: CRF forward (one block per batch, trans in LDS) ----------------
__global__ void k5_crf(const float* __restrict__ emit, const float* __restrict__ trans,
                       float* __restrict__ apath)
{
    const int b = blockIdx.x, j = threadIdx.x;   // 64 threads
    __shared__ float trl[L_][L_+1];              // trl[i][j] = trans[i*48+j]
    __shared__ float albuf[2][64];
    for (int q = j; q < L_*L_; q += 64) trl[q/L_][q%L_] = trans[q];
    __syncthreads();
    float a = -3.0e38f;
    if (j < L_) a = emit[((size_t)b*T_)*L_ + j] + trl[1][j];   // alpha0, BOS row
    for (int t=1; t<T_; t++) {
        albuf[t&1][j] = a;
        __syncthreads();
        if (j < L_) {
            const float* buf = albuf[t&1];
            float m = -3.4e38f;
            #pragma unroll
            for (int i=0;i<L_;i++) m = fmaxf(m, buf[i] + trl[i][j]);
            float sum = 0.f;
            #pragma unroll
            for (int i=0;i<L_;i++) sum += __expf(buf[i] + trl[i][j] - m);
            a = m + __logf(sum) + emit[((size_t)b*T_ + t)*L_ + j];
        }
    }
    if (j == 2) apath[b] = a;    // EOS=2
}

// ---------------- K6: final scalar ----------------
__global__ void k6_final(const float* __restrict__ apath, const float* __restrict__ gold, float* out)
{
    if (threadIdx.x==0 && blockIdx.x==0) {
        float s=0.f;
        for (int b=0;b<B_;b++) s += apath[b];
        out[0] = (s - gold[0]) / (float)B_;
    }
}

extern "C" void kernel_launch(void* const* d_in, const int* in_sizes, int n_in,
                              void* d_out, int out_size, void* d_ws, size_t ws_size,
                              hipStream_t stream)
{
    const int*   src     = (const int*)d_in[0];
    const int*   targets = (const int*)d_in[2];
    const float* emb     = (const float*)d_in[3];
    const float* wih_f   = (const float*)d_in[4];
    const float* whh_f   = (const float*)d_in[5];
    const float* b_f     = (const float*)d_in[6];
    const float* wih_b   = (const float*)d_in[7];
    const float* whh_b   = (const float*)d_in[8];
    const float* b_b     = (const float*)d_in[9];
    const float* wemit   = (const float*)d_in[10];
    const float* bemit   = (const float*)d_in[11];
    const float* trans   = (const float*)d_in[12];

    char* ws = (char*)d_ws;
    size_t off = 0;
    auto alloc = [&](size_t bytes) -> void* {
        void* p = ws + off; off += (bytes + 255) & ~(size_t)255; return p;
    };
    bf16*  wcat  = (bf16*)alloc((size_t)NCOL*E_*2);      // 2 MB
    bf16*  whh   = (bf16*)alloc((size_t)2*G4*H_*2);      // 4 MB
    bf16*  wem   = (bf16*)alloc((size_t)L_*1024*2);      // 96 KB
    bf16*  x     = (bf16*)alloc((size_t)BT*E_*2);        // 8 MB
    bf16*  xg    = (bf16*)alloc((size_t)BT*NCOL*2);      // 128 MB (permuted layout)
    bf16*  h_st  = (bf16*)alloc((size_t)2*BT*H_*2);      // 32 MB ([d][t][hblk][b][16])
    float* emit  = (float*)alloc((size_t)BT*L_*4);       // 3 MB
    u64*   hx    = (u64*)alloc((size_t)2*2*8192*8);      // 256 KB tagged exchange
    float* gold  = (float*)alloc(256);
    float* apath = gold + 1;

    if (off > ws_size) {
        fprintf(stderr, "kernel_launch: workspace too small: need %zu, have %zu\n", off, ws_size);
        return;
    }

    // zero tagged exchange (kills stale tags from prior replays) + gold/apath
    hipMemsetAsync(hx, 0, (size_t)2*2*8192*8 + 256, stream);

    k0_prep<<<4096, 256, 0, stream>>>(wih_f, wih_b, whh_f, whh_b, wemit, emb, src,
                                      wcat, whh, wem, x);
    k1_xg<<<dim3(BT/64, NCOL/64), 256, 0, stream>>>(x, wcat, b_f, b_b, xg);
    k2_scan<<<64, 256, 0, stream>>>(whh, xg, h_st, hx);
    k3_emit<<<BT/64, 256, 0, stream>>>(h_st, wem, bemit, emit);
    k4_golden<<<64, 256, 0, stream>>>(emit, targets, trans, gold);
    k5_crf<<<B_, 64, 0, stream>>>(emit, trans, apath);
    k6_final<<<1, 64, 0, stream>>>(apath, gold, (float*)d_out);
}